// Round 4
// baseline (6109.969 us; speedup 1.0000x reference)
//
#include <hip/hip_runtime.h>

#define DEV __device__ __forceinline__

namespace {

constexpr int B_ = 8;
constexpr int N_ = 1024;
constexpr int M_ = 256;
constexpr int D_ = 25;
constexpr int FH_ = 240;
constexpr int NATOM = B_ * N_;          // 8192
constexpr float CSC = 1.0f / 256.0f;    // 4/(NN*NTYPES*4)
constexpr int WROW = 28;                // W row pad: 28 floats = 112 B (16B-aligned)

DEV float fast_tanh(float x) {
  float ax = fabsf(x);
  float e = __expf(-2.0f * ax);
  float r = (1.0f - e) * __builtin_amdgcn_rcpf(1.0f + e);
  return copysignf(r, x);
}

// Geometry: normalized descriptor channels blk[4]; optionally the 4x3
// normalized Jacobian rid[12].
template <bool WANT_RID>
DEV void compute_geom(float dx, float dy, float dz, int nb, int t, int m,
                      const float* __restrict__ davg, const float* __restrict__ dstd,
                      float* __restrict__ blk, float* __restrict__ rid) {
  float mf = (nb > 0) ? 1.0f : 0.0f;
  float dr2 = dx * dx + dy * dy + dz * dz;
  float safe = (nb > 0) ? dr2 : 1.0f;
  float rs = __builtin_amdgcn_rsqf(safe);   // 1/sqrt
  float rij = safe * rs;
  float inr = mf * rs;
  float x = rij * mf;
  float inr2 = inr * inr;
  float inr4 = inr2 * inr2;
  float inr3 = inr4 * x;
  float u = (x - 5.8f) * 5.0f;
  float uu = u * u;
  float A = -6.0f * uu + 15.0f * u - 10.0f;
  float poly = uu * u * A + 1.0f;
  float dpoly = (3.0f * uu * A + uu * u * (-12.0f * u + 15.0f)) * 5.0f;
  bool mid = (x >= 5.8f) && (x < 6.0f);
  float vv = ((x < 5.8f) ? 1.0f : (mid ? poly : 0.0f)) * mf;
  float dvv = (mid ? dpoly : 0.0f) * mf;
  float pre[4];
  pre[0] = inr;
  pre[1] = dx * inr2;
  pre[2] = dy * inr2;
  pre[3] = dz * inr2;
  int bidx = (t * M_ + m) * 4;
  float4 av = *(const float4*)(davg + bidx);
  float4 sv = *(const float4*)(dstd + bidx);
  float avf[4] = {av.x, av.y, av.z, av.w};
  float rsv[4] = {__builtin_amdgcn_rcpf(sv.x), __builtin_amdgcn_rcpf(sv.y),
                  __builtin_amdgcn_rcpf(sv.z), __builtin_amdgcn_rcpf(sv.w)};
#pragma unroll
  for (int d = 0; d < 4; ++d) blk[d] = (pre[d] * vv - avf[d]) * rsv[d];
  if (WANT_RID) {
    float dv[3] = {dx, dy, dz};
    float ci = dvv * inr;
    float com[3];
#pragma unroll
    for (int c = 0; c < 3; ++c) com[c] = ci * dv[c];
    float iv = inr3 * vv;
#pragma unroll
    for (int c = 0; c < 3; ++c)
      rid[c] = (dv[c] * iv - pre[0] * com[c]) * mf * rsv[0];
#pragma unroll
    for (int r = 0; r < 3; ++r) {
#pragma unroll
      for (int c = 0; c < 3; ++c) {
        float outer = 2.0f * dv[r] * dv[c] * inr4 - ((r == c) ? inr2 : 0.0f);
        rid[(1 + r) * 3 + c] = (outer * vv - pre[1 + r] * com[c]) * mf * rsv[1 + r];
      }
    }
  }
}

// Cooperative staging of the block's two embedding-weight pairs into LDS.
// Rows padded to WROW floats so ds_read_b128 stays 16B-aligned.
DEV void stage_weights(int t, int m,
                       const float* __restrict__ eW0, const float* __restrict__ eb0,
                       const float* __restrict__ eW1, const float* __restrict__ eb1,
                       const float* __restrict__ eW2, const float* __restrict__ eb2,
                       float (*sW1)[D_ * WROW], float (*sW2)[D_ * WROW],
                       float (*sWb)[4 * WROW]) {
  for (int idx = m; idx < 2 * 625; idx += 256) {
    int h = idx / 625;
    int r = idx - h * 625;
    int pp = t * 2 + h;
    int f = r / 25, e = r - f * 25;
    sW1[h][f * WROW + e] = eW1[pp * 625 + r];
    sW2[h][f * WROW + e] = eW2[pp * 625 + r];
  }
  if (m < 50) {
    int h = m / 25, e = m - h * 25;
    int pp = t * 2 + h;
    sWb[h][0 * WROW + e] = eW0[pp * 25 + e];
    sWb[h][1 * WROW + e] = eb0[pp * 25 + e];
    sWb[h][2 * WROW + e] = eb1[pp * 25 + e];
    sWb[h][3 * WROW + e] = eb2[pp * 25 + e];
  }
}

// K1: embedding fwd per neighbor; weights from LDS (ds_read), activations in
// regs (~70 live). Then acc[4][25] via transposed-LDS float4 reduction.
__global__ __launch_bounds__(256, 3) void k_embed_acc(
    const float* __restrict__ dR, const int* __restrict__ neigh,
    const float* __restrict__ davg, const float* __restrict__ dstd,
    const float* __restrict__ eW0, const float* __restrict__ eb0,
    const float* __restrict__ eW1, const float* __restrict__ eb1,
    const float* __restrict__ eW2, const float* __restrict__ eb2,
    float* __restrict__ acc_ws) {
  __shared__ float sW1[2][D_ * WROW];
  __shared__ float sW2[2][D_ * WROW];
  __shared__ float sWb[2][4 * WROW];
  __shared__ float sGT[D_][260];   // stride 260: +4 pad for b128 tail reads
  __shared__ float sBT[4][260];
  int atom = blockIdx.x;
  int n = atom & (N_ - 1);
  int t = (n >= 512) ? 1 : 0;
  int m = threadIdx.x;
  stage_weights(t, m, eW0, eb0, eW1, eb1, eW2, eb2, sW1, sW2, sWb);
  int base = atom * M_ + m;
  float dx = dR[base * 3 + 0];
  float dy = dR[base * 3 + 1];
  float dz = dR[base * 3 + 2];
  int nb = neigh[base];
  float blk[4];
  compute_geom<false>(dx, dy, dz, nb, t, m, davg, dstd, blk, nullptr);
  __syncthreads();
  int half = m >> 7;
  const float* W1 = &sW1[half][0];
  const float* W2 = &sW2[half][0];
  const float* Wb = &sWb[half][0];
  float s0 = blk[0];
  float H[D_], a[D_];
#pragma unroll
  for (int e = 0; e < D_; ++e)
    H[e] = fast_tanh(fmaf(s0, Wb[e], Wb[WROW + e]));  // h0
#pragma unroll
  for (int e = 0; e < D_; ++e) a[e] = Wb[2 * WROW + e];  // b1
#pragma unroll
  for (int f = 0; f < D_; ++f) {
    float hf = H[f];
#pragma unroll
    for (int e = 0; e < D_; ++e) a[e] = fmaf(hf, W1[f * WROW + e], a[e]);
  }
#pragma unroll
  for (int e = 0; e < D_; ++e) H[e] += fast_tanh(a[e]);  // h1
#pragma unroll
  for (int e = 0; e < D_; ++e) a[e] = Wb[3 * WROW + e];  // b2
#pragma unroll
  for (int f = 0; f < D_; ++f) {
    float hf = H[f];
#pragma unroll
    for (int e = 0; e < D_; ++e) a[e] = fmaf(hf, W2[f * WROW + e], a[e]);
  }
#pragma unroll
  for (int e = 0; e < D_; ++e) sGT[e][m] = H[e] + fast_tanh(a[e]);  // G
#pragma unroll
  for (int d = 0; d < 4; ++d) sBT[d][m] = blk[d];
  __syncthreads();
  if (threadIdx.x < 100) {
    int e = threadIdx.x >> 2;
    int d = threadIdx.x & 3;
    const float4* g4 = (const float4*)(&sGT[e][0]);
    const float4* b4 = (const float4*)(&sBT[d][0]);
    float sum = 0.0f;
    for (int k = 0; k < 64; ++k) {
      float4 g = g4[k];
      float4 b = b4[k];
      sum += b.x * g.x + b.y * g.y + b.z * g.z + b.w * g.w;
    }
    acc_ws[atom * 100 + d * D_ + e] = sum * CSC;
  }
}

// K2: 8 atoms per block. DRt + fitting net fwd + bwd, emits Ei/Etot and dacc.
__global__ __launch_bounds__(256) void k_fit(
    const float* __restrict__ acc_ws,
    const float* __restrict__ fW0, const float* __restrict__ fb0,
    const float* __restrict__ fW1, const float* __restrict__ fb1,
    const float* __restrict__ fW2, const float* __restrict__ fb2,
    const float* __restrict__ fW3, const float* __restrict__ fb3,
    const float* __restrict__ ener_shift,
    float* __restrict__ dacc_ws, float* __restrict__ out) {
  constexpr int AB = 8;
  __shared__ float sAcc[AB][100];
  __shared__ float sX[AB][400];   // x fwd, then dx bwd
  __shared__ float sH0[AB][FH_];  // h0, then g0
  __shared__ float sT1[AB][FH_];  // tanh1, then g1
  __shared__ float sH1[AB][FH_];  // h1, then dh1
  __shared__ float sT2[AB][FH_];  // tanh2, then g2
  __shared__ float sEi[AB];
  int a0 = blockIdx.x * AB;
  int bb = a0 >> 10;
  int n0 = a0 & (N_ - 1);
  int t = (n0 >= 512) ? 1 : 0;
  int tid = threadIdx.x;
  for (int idx = tid; idx < AB * 100; idx += 256)
    ((float*)sAcc)[idx] = acc_ws[a0 * 100 + idx];
  if (tid < AB) sEi[tid] = 0.0f;
  __syncthreads();
  for (int idx = tid; idx < AB * 400; idx += 256) {
    int a = idx / 400; int r = idx % 400; int e = r >> 4; int f = r & 15;
    const float* A = sAcc[a];
    sX[a][r] = A[e] * A[f] + A[25 + e] * A[25 + f] + A[50 + e] * A[50 + f] +
               A[75 + e] * A[75 + f];
  }
  __syncthreads();
  const float* W0 = fW0 + t * 400 * FH_;
  const float* W1 = fW1 + t * FH_ * FH_;
  const float* W2 = fW2 + t * FH_ * FH_;
  const float* B0 = fb0 + t * FH_;
  const float* B1 = fb1 + t * FH_;
  const float* B2 = fb2 + t * FH_;
  const float* W3 = fW3 + t * FH_;
  int j = tid;
  if (j < FH_) {  // layer 0: 400 -> 240
    float acc8[AB];
#pragma unroll
    for (int a = 0; a < AB; ++a) acc8[a] = B0[j];
    for (int i = 0; i < 400; ++i) {
      float w = W0[i * FH_ + j];
#pragma unroll
      for (int a = 0; a < AB; ++a) acc8[a] = fmaf(sX[a][i], w, acc8[a]);
    }
#pragma unroll
    for (int a = 0; a < AB; ++a) sH0[a][j] = fast_tanh(acc8[a]);
  }
  __syncthreads();
  if (j < FH_) {  // layer 1 (residual)
    float acc8[AB];
#pragma unroll
    for (int a = 0; a < AB; ++a) acc8[a] = B1[j];
    for (int f = 0; f < FH_; ++f) {
      float w = W1[f * FH_ + j];
#pragma unroll
      for (int a = 0; a < AB; ++a) acc8[a] = fmaf(sH0[a][f], w, acc8[a]);
    }
#pragma unroll
    for (int a = 0; a < AB; ++a) {
      float tv = fast_tanh(acc8[a]);
      sT1[a][j] = tv;
      sH1[a][j] = sH0[a][j] + tv;
    }
  }
  __syncthreads();
  if (j < FH_) {  // layer 2 (residual) + Ei dot
    float acc8[AB];
#pragma unroll
    for (int a = 0; a < AB; ++a) acc8[a] = B2[j];
    for (int f = 0; f < FH_; ++f) {
      float w = W2[f * FH_ + j];
#pragma unroll
      for (int a = 0; a < AB; ++a) acc8[a] = fmaf(sH1[a][f], w, acc8[a]);
    }
    float w3 = W3[j];
#pragma unroll
    for (int a = 0; a < AB; ++a) {
      float tv = fast_tanh(acc8[a]);
      sT2[a][j] = tv;
      atomicAdd(&sEi[a], (sH1[a][j] + tv) * w3);
    }
  }
  __syncthreads();
  if (tid < AB) {
    float ei = sEi[tid] + fb3[t] + ener_shift[t];
    out[8 + a0 + tid] = ei;            // Ei
    sEi[tid] = ei;
  }
  if (j < FH_) {  // g2 = W3 * (1 - t2^2)   (dEi = 1)
    float w3 = W3[j];
#pragma unroll
    for (int a = 0; a < AB; ++a) {
      float tv = sT2[a][j];
      sT2[a][j] = w3 * (1.0f - tv * tv);
    }
  }
  __syncthreads();
  if (tid == 0) {
    float s = sEi[0] + sEi[1] + sEi[2] + sEi[3] + sEi[4] + sEi[5] + sEi[6] + sEi[7];
    atomicAdd(&out[bb], s);
  }
  if (j < FH_) {  // dh1 = W3 + g2 @ W2^T ; g1 = dh1*(1-t1^2)
    float w3 = W3[j];
    float acc8[AB];
#pragma unroll
    for (int a = 0; a < AB; ++a) acc8[a] = w3;
    for (int k = 0; k < FH_; ++k) {
      float w = W2[j * FH_ + k];
#pragma unroll
      for (int a = 0; a < AB; ++a) acc8[a] = fmaf(sT2[a][k], w, acc8[a]);
    }
#pragma unroll
    for (int a = 0; a < AB; ++a) {
      float dh1 = acc8[a];
      float tv = sT1[a][j];
      sH1[a][j] = dh1;
      sT1[a][j] = dh1 * (1.0f - tv * tv);
    }
  }
  __syncthreads();
  if (j < FH_) {  // dh0 = dh1 + g1 @ W1^T ; g0 = dh0*(1-h0^2)
    float acc8[AB];
#pragma unroll
    for (int a = 0; a < AB; ++a) acc8[a] = sH1[a][j];
    for (int k = 0; k < FH_; ++k) {
      float w = W1[j * FH_ + k];
#pragma unroll
      for (int a = 0; a < AB; ++a) acc8[a] = fmaf(sT1[a][k], w, acc8[a]);
    }
#pragma unroll
    for (int a = 0; a < AB; ++a) {
      float h0v = sH0[a][j];
      sH0[a][j] = acc8[a] * (1.0f - h0v * h0v);
    }
  }
  __syncthreads();
  for (int i = tid; i < 400; i += 256) {  // dx = g0 @ W0^T
    float acc8[AB];
#pragma unroll
    for (int a = 0; a < AB; ++a) acc8[a] = 0.0f;
    for (int jj = 0; jj < FH_; ++jj) {
      float w = W0[i * FH_ + jj];
#pragma unroll
      for (int a = 0; a < AB; ++a) acc8[a] = fmaf(sH0[a][jj], w, acc8[a]);
    }
#pragma unroll
    for (int a = 0; a < AB; ++a) sX[a][i] = acc8[a];
  }
  __syncthreads();
  for (int idx = tid; idx < AB * 100; idx += 256) {
    int a = idx / 100; int r = idx % 100; int d = r / 25; int e = r % 25;
    const float* A = sAcc[a];
    const float* DX = sX[a];
    float sum = 0.0f;
#pragma unroll
    for (int f = 0; f < 16; ++f) sum = fmaf(DX[e * 16 + f], A[d * 25 + f], sum);
    if (e < 16) {
#pragma unroll
      for (int e2 = 0; e2 < 25; ++e2) sum = fmaf(DX[e2 * 16 + e], A[d * 25 + e2], sum);
    }
    dacc_ws[a0 * 100 + idx] = sum;
  }
}

// K3: embedding fwd + VJP per neighbor; weights from LDS, activations in regs
// (X/T/a/Y = 100, peak ~135 live; h0 recovered as h1 - t1). Direct scatter
// atomics to out (atomics were never the limiter; R3 showed WRITE ~ atomic
// count regardless of spreading).
__global__ __launch_bounds__(256, 3) void k_bwd_force(
    const float* __restrict__ dR, const int* __restrict__ neigh,
    const float* __restrict__ davg, const float* __restrict__ dstd,
    const float* __restrict__ eW0, const float* __restrict__ eb0,
    const float* __restrict__ eW1, const float* __restrict__ eb1,
    const float* __restrict__ eW2, const float* __restrict__ eb2,
    const float* __restrict__ dacc_ws, float* __restrict__ out) {
  __shared__ float sW1[2][D_ * WROW];
  __shared__ float sW2[2][D_ * WROW];
  __shared__ float sWb[2][4 * WROW];
  __shared__ float sF[3];
  int atom = blockIdx.x;
  int bb = atom >> 10;
  int n = atom & (N_ - 1);
  int t = (n >= 512) ? 1 : 0;
  int m = threadIdx.x;
  if (m < 3) sF[m] = 0.0f;
  stage_weights(t, m, eW0, eb0, eW1, eb1, eW2, eb2, sW1, sW2, sWb);
  const float* dac = dacc_ws + atom * 100;  // block-uniform
  int base = atom * M_ + m;
  float dx = dR[base * 3 + 0];
  float dy = dR[base * 3 + 1];
  float dz = dR[base * 3 + 2];
  int nb = neigh[base];
  float blk[4];
  compute_geom<false>(dx, dy, dz, nb, t, m, davg, dstd, blk, nullptr);
  __syncthreads();
  int half = m >> 7;
  const float* W1 = &sW1[half][0];
  const float* W2 = &sW2[half][0];
  const float* Wb = &sWb[half][0];
  float s0 = blk[0];
  float X[D_], T[D_], a[D_], Y[D_];
  // stage A: X = h0
#pragma unroll
  for (int e = 0; e < D_; ++e)
    X[e] = fast_tanh(fmaf(s0, Wb[e], Wb[WROW + e]));
  // stage B: a1 = b1 + h0@W1 ; T = t1 ; X = h1
#pragma unroll
  for (int e = 0; e < D_; ++e) a[e] = Wb[2 * WROW + e];
#pragma unroll
  for (int f = 0; f < D_; ++f) {
    float hf = X[f];
#pragma unroll
    for (int e = 0; e < D_; ++e) a[e] = fmaf(hf, W1[f * WROW + e], a[e]);
  }
#pragma unroll
  for (int e = 0; e < D_; ++e) {
    T[e] = fast_tanh(a[e]);
    X[e] += T[e];  // h1
  }
  // stage C: a2 = b2 + h1@W2
#pragma unroll
  for (int e = 0; e < D_; ++e) a[e] = Wb[3 * WROW + e];
#pragma unroll
  for (int f = 0; f < D_; ++f) {
    float hf = X[f];
#pragma unroll
    for (int e = 0; e < D_; ++e) a[e] = fmaf(hf, W2[f * WROW + e], a[e]);
  }
  // stage D: t2 -> G -> dblk ; a := dG ; Y := g2
  float dblk0 = 0.0f, dblk1 = 0.0f, dblk2 = 0.0f, dblk3 = 0.0f;
#pragma unroll
  for (int e = 0; e < D_; ++e) {
    float t2 = fast_tanh(a[e]);
    float G = X[e] + t2;
    dblk0 = fmaf(dac[e], G, dblk0);
    dblk1 = fmaf(dac[25 + e], G, dblk1);
    dblk2 = fmaf(dac[50 + e], G, dblk2);
    dblk3 = fmaf(dac[75 + e], G, dblk3);
    float dGe = CSC * (dac[e] * blk[0] + dac[25 + e] * blk[1] +
                       dac[50 + e] * blk[2] + dac[75 + e] * blk[3]);
    Y[e] = dGe * (1.0f - t2 * t2);  // g2
    a[e] = dGe;                     // dG
  }
  // stage E: a := dh1 = dG + g2@W2^T  (W2^T row e = sW2 row e, contiguous)
#pragma unroll
  for (int e = 0; e < D_; ++e) {
    float s = a[e];
#pragma unroll
    for (int f = 0; f < D_; ++f) s = fmaf(Y[f], W2[e * WROW + f], s);
    a[e] = s;
  }
  // gate: Y := g1 = dh1*(1-t1^2)
#pragma unroll
  for (int e = 0; e < D_; ++e) Y[e] = a[e] * (1.0f - T[e] * T[e]);
  // stage F: dsum = sum_e (dh1 + g1@W1^T)[e] * (1-h0^2) * W0[e] ; h0 = h1-t1
  float dsum = 0.0f;
#pragma unroll
  for (int e = 0; e < D_; ++e) {
    float s = a[e];
#pragma unroll
    for (int f = 0; f < D_; ++f) s = fmaf(Y[f], W1[e * WROW + f], s);
    float h0e = X[e] - T[e];
    dsum = fmaf(s * (1.0f - h0e * h0e), Wb[e], dsum);
  }
  float dE0 = dblk0 * CSC + dsum;
  float dE1 = dblk1 * CSC;
  float dE2 = dblk2 * CSC;
  float dE3 = dblk3 * CSC;
  // recompute geometry Jacobian
  float blkb[4], rid[12];
  compute_geom<true>(dx, dy, dz, nb, t, m, davg, dstd, blkb, rid);
  float px = dE0 * rid[0] + dE1 * rid[3] + dE2 * rid[6] + dE3 * rid[9];
  float py = dE0 * rid[1] + dE1 * rid[4] + dE2 * rid[7] + dE3 * rid[10];
  float pz = dE0 * rid[2] + dE1 * rid[5] + dE2 * rid[8] + dE3 * rid[11];
  // wave-level butterfly reduce, then one LDS atomic per wave
  float rx = px, ry = py, rz = pz;
#pragma unroll
  for (int off = 32; off > 0; off >>= 1) {
    rx += __shfl_down(rx, off, 64);
    ry += __shfl_down(ry, off, 64);
    rz += __shfl_down(rz, off, 64);
  }
  if ((m & 63) == 0) {
    atomicAdd(&sF[0], rx);
    atomicAdd(&sF[1], ry);
    atomicAdd(&sF[2], rz);
  }
  if (nb > 0) {  // scatter to neighbor j = nb-1
    int jn = nb - 1;
    int fi = 8 + NATOM + (bb * N_ + jn) * 3;
    atomicAdd(&out[fi + 0], px);
    atomicAdd(&out[fi + 1], py);
    atomicAdd(&out[fi + 2], pz);
  }
  __syncthreads();
  if (m < 3) atomicAdd(&out[8 + NATOM + atom * 3 + m], -sF[m]);
}

}  // namespace

extern "C" void kernel_launch(void* const* d_in, const int* in_sizes, int n_in,
                              void* d_out, int out_size, void* d_ws, size_t ws_size,
                              hipStream_t stream) {
  (void)in_sizes; (void)n_in; (void)ws_size;
  const float* image_dR   = (const float*)d_in[0];
  const int*   list_neigh = (const int*)d_in[1];
  const float* davg       = (const float*)d_in[2];
  const float* dstd       = (const float*)d_in[3];
  const float* eW0        = (const float*)d_in[4];
  const float* eb0        = (const float*)d_in[5];
  const float* eW1        = (const float*)d_in[6];
  const float* eb1        = (const float*)d_in[7];
  const float* eW2        = (const float*)d_in[8];
  const float* eb2        = (const float*)d_in[9];
  const float* fW0        = (const float*)d_in[10];
  const float* fb0        = (const float*)d_in[11];
  const float* fW1        = (const float*)d_in[12];
  const float* fb1        = (const float*)d_in[13];
  const float* fW2        = (const float*)d_in[14];
  const float* fb2        = (const float*)d_in[15];
  const float* fW3        = (const float*)d_in[16];
  const float* fb3        = (const float*)d_in[17];
  const float* ener_shift = (const float*)d_in[18];
  float* out = (float*)d_out;
  float* acc_ws  = (float*)d_ws;                  // 8192*100 floats
  float* dacc_ws = acc_ws + NATOM * 100;          // 8192*100 floats

  hipMemsetAsync(d_out, 0, (size_t)out_size * sizeof(float), stream);
  k_embed_acc<<<NATOM, 256, 0, stream>>>(image_dR, list_neigh, davg, dstd,
                                         eW0, eb0, eW1, eb1, eW2, eb2, acc_ws);
  k_fit<<<NATOM / 8, 256, 0, stream>>>(acc_ws, fW0, fb0, fW1, fb1, fW2, fb2,
                                       fW3, fb3, ener_shift, dacc_ws, out);
  k_bwd_force<<<NATOM, 256, 0, stream>>>(image_dR, list_neigh, davg, dstd,
                                         eW0, eb0, eW1, eb1, eW2, eb2,
                                         dacc_ws, out);
}

// Round 5
// 1150.349 us; speedup vs baseline: 5.3114x; 5.3114x over previous
//
#include <hip/hip_runtime.h>

#define DEV __device__ __forceinline__

// ---- repetition macros (25-wide, two independent copies for nesting) ----
#define RA(F) F(0) F(1) F(2) F(3) F(4) F(5) F(6) F(7) F(8) F(9) F(10) F(11) \
  F(12) F(13) F(14) F(15) F(16) F(17) F(18) F(19) F(20) F(21) F(22) F(23) F(24)
#define RB(F,j) F(j,0) F(j,1) F(j,2) F(j,3) F(j,4) F(j,5) F(j,6) F(j,7) F(j,8) \
  F(j,9) F(j,10) F(j,11) F(j,12) F(j,13) F(j,14) F(j,15) F(j,16) F(j,17) \
  F(j,18) F(j,19) F(j,20) F(j,21) F(j,22) F(j,23) F(j,24)
#define AP8(F) F(0) F(1) F(2) F(3) F(4) F(5) F(6) F(7)

namespace {

constexpr int B_ = 8;
constexpr int N_ = 1024;
constexpr int M_ = 256;
constexpr int D_ = 25;
constexpr int FH_ = 240;
constexpr int NATOM = B_ * N_;          // 8192
constexpr float CSC = 1.0f / 256.0f;    // 4/(NN*NTYPES*4)

DEV float fast_tanh(float x) {
  float ax = fabsf(x);
  float e = __expf(-2.0f * ax);
  float r = (1.0f - e) * __builtin_amdgcn_rcpf(1.0f + e);
  return copysignf(r, x);
}

// Normalized descriptor channels (pure scalars — no arrays, SROA-safe).
DEV void geom_blk(float dx, float dy, float dz, int nb, int t, int m,
                  const float* __restrict__ davg, const float* __restrict__ dstd,
                  float& o0, float& o1, float& o2, float& o3) {
  float mf = (nb > 0) ? 1.0f : 0.0f;
  float dr2 = dx * dx + dy * dy + dz * dz;
  float safe = (nb > 0) ? dr2 : 1.0f;
  float rs = __builtin_amdgcn_rsqf(safe);
  float rij = safe * rs;
  float inr = mf * rs;
  float x = rij * mf;
  float inr2 = inr * inr;
  float u = (x - 5.8f) * 5.0f;
  float uu = u * u;
  float A = -6.0f * uu + 15.0f * u - 10.0f;
  float poly = uu * u * A + 1.0f;
  bool mid = (x >= 5.8f) && (x < 6.0f);
  float vv = ((x < 5.8f) ? 1.0f : (mid ? poly : 0.0f)) * mf;
  int bidx = (t * M_ + m) * 4;
  float4 av = *(const float4*)(davg + bidx);
  float4 sv = *(const float4*)(dstd + bidx);
  o0 = (inr * vv - av.x) * __builtin_amdgcn_rcpf(sv.x);
  o1 = (dx * inr2 * vv - av.y) * __builtin_amdgcn_rcpf(sv.y);
  o2 = (dy * inr2 * vv - av.z) * __builtin_amdgcn_rcpf(sv.z);
  o3 = (dz * inr2 * vv - av.w) * __builtin_amdgcn_rcpf(sv.w);
}

// Jacobian folded straight into the force projection (no rid[12] array).
DEV void geom_force(float dx, float dy, float dz, int nb, int t, int m,
                    const float* __restrict__ dstd,
                    float dE0, float dE1, float dE2, float dE3,
                    float& px, float& py, float& pz) {
  float mf = (nb > 0) ? 1.0f : 0.0f;
  float dr2 = dx * dx + dy * dy + dz * dz;
  float safe = (nb > 0) ? dr2 : 1.0f;
  float rs = __builtin_amdgcn_rsqf(safe);
  float rij = safe * rs;
  float inr = mf * rs;
  float x = rij * mf;
  float inr2 = inr * inr;
  float inr4 = inr2 * inr2;
  float inr3 = inr4 * x;
  float u = (x - 5.8f) * 5.0f;
  float uu = u * u;
  float A = -6.0f * uu + 15.0f * u - 10.0f;
  float poly = uu * u * A + 1.0f;
  float dpoly = (3.0f * uu * A + uu * u * (-12.0f * u + 15.0f)) * 5.0f;
  bool mid = (x >= 5.8f) && (x < 6.0f);
  float vv = ((x < 5.8f) ? 1.0f : (mid ? poly : 0.0f)) * mf;
  float dvv = (mid ? dpoly : 0.0f) * mf;
  int bidx = (t * M_ + m) * 4;
  float4 sv = *(const float4*)(dstd + bidx);
  float e0 = dE0 * mf * __builtin_amdgcn_rcpf(sv.x);
  float e1 = dE1 * mf * __builtin_amdgcn_rcpf(sv.y);
  float e2 = dE2 * mf * __builtin_amdgcn_rcpf(sv.z);
  float e3 = dE3 * mf * __builtin_amdgcn_rcpf(sv.w);
  float ci = dvv * inr;
  float comx = ci * dx, comy = ci * dy, comz = ci * dz;
  float iv = inr3 * vv;
  float pre0 = inr, pre1 = dx * inr2, pre2 = dy * inr2, pre3 = dz * inr2;
  float txx = 2.0f * dx * dx * inr4 - inr2;
  float tyy = 2.0f * dy * dy * inr4 - inr2;
  float tzz = 2.0f * dz * dz * inr4 - inr2;
  float txy = 2.0f * dx * dy * inr4;
  float txz = 2.0f * dx * dz * inr4;
  float tyz = 2.0f * dy * dz * inr4;
  px = e0 * (dx * iv - pre0 * comx) + e1 * (txx * vv - pre1 * comx) +
       e2 * (txy * vv - pre2 * comx) + e3 * (txz * vv - pre3 * comx);
  py = e0 * (dy * iv - pre0 * comy) + e1 * (txy * vv - pre1 * comy) +
       e2 * (tyy * vv - pre2 * comy) + e3 * (tyz * vv - pre3 * comy);
  pz = e0 * (dz * iv - pre0 * comz) + e1 * (txz * vv - pre1 * comz) +
       e2 * (tyz * vv - pre2 * comz) + e3 * (tzz * vv - pre3 * comz);
}

// ---- K1 macro bodies: embedding forward, all named scalars ----
#define K1H0(e) float h##e = fast_tanh(fmaf(s0, W0p[e], b0p[e]));
#define K1A1(e) float a##e = b1p[e];
#define K1M1E(f,e) a##e = fmaf(hf, W1p[(f)*25+(e)], a##e);
#define K1M1R(f) { const float hf = h##f; RB(K1M1E, f) }
#define K1H1(e) h##e += fast_tanh(a##e);
#define K1A2(e) a##e = b2p[e];
#define K1M2E(f,e) a##e = fmaf(hf, W2p[(f)*25+(e)], a##e);
#define K1M2R(f) { const float hf = h##f; RB(K1M2E, f) }
#define K1ST(e) sGT[e][m] = h##e + fast_tanh(a##e);

// K1: per atom (block) x neighbor (thread): geometry + embed fwd, then
// acc[4][25] via transposed-LDS float4 reduction.
__global__ __launch_bounds__(256, 4) void k_embed_acc(
    const float* __restrict__ dR, const int* __restrict__ neigh,
    const float* __restrict__ davg, const float* __restrict__ dstd,
    const float* __restrict__ eW0, const float* __restrict__ eb0,
    const float* __restrict__ eW1, const float* __restrict__ eb1,
    const float* __restrict__ eW2, const float* __restrict__ eb2,
    float* __restrict__ acc_ws) {
  __shared__ float sGT[D_][260];   // row stride 260 floats: rows 16B-aligned
  __shared__ float sBT[4][260];
  int atom = blockIdx.x;
  int n = atom & (N_ - 1);
  int t = (n >= 512) ? 1 : 0;
  int m = threadIdx.x;
  int p = __builtin_amdgcn_readfirstlane(t * 2 + (m >> 7));  // wave-uniform
  const float* W0p = eW0 + p * D_;
  const float* b0p = eb0 + p * D_;
  const float* W1p = eW1 + p * 625;
  const float* b1p = eb1 + p * D_;
  const float* W2p = eW2 + p * 625;
  const float* b2p = eb2 + p * D_;
  int base = atom * M_ + m;
  float dx = dR[base * 3 + 0];
  float dy = dR[base * 3 + 1];
  float dz = dR[base * 3 + 2];
  int nb = neigh[base];
  float bb0, bb1, bb2, bb3;
  geom_blk(dx, dy, dz, nb, t, m, davg, dstd, bb0, bb1, bb2, bb3);
  float s0 = bb0;
  RA(K1H0)
  RA(K1A1)
  RA(K1M1R)
  RA(K1H1)
  RA(K1A2)
  RA(K1M2R)
  RA(K1ST)
  sBT[0][m] = bb0; sBT[1][m] = bb1; sBT[2][m] = bb2; sBT[3][m] = bb3;
  __syncthreads();
  if (threadIdx.x < 100) {
    int e = threadIdx.x >> 2;
    int d = threadIdx.x & 3;
    const float4* g4 = (const float4*)(&sGT[e][0]);
    const float4* b4 = (const float4*)(&sBT[d][0]);
    float sum = 0.0f;
    for (int k = 0; k < 64; ++k) {
      float4 g = g4[k];
      float4 b = b4[k];
      sum += b.x * g.x + b.y * g.y + b.z * g.z + b.w * g.w;
    }
    acc_ws[atom * 100 + d * D_ + e] = sum * CSC;
  }
}

// ---- K2 macro bodies: 8 named accumulators ----
#define DECL8(v) float c0=(v),c1=(v),c2=(v),c3=(v),c4=(v),c5=(v),c6=(v),c7=(v);
#define F8X(q)  c##q = fmaf(sX[q][i], w, c##q);
#define F8H0(q) c##q = fmaf(sH0[q][f], w, c##q);
#define F8H1(q) c##q = fmaf(sH1[q][f], w, c##q);
#define F8T2(q) c##q = fmaf(sT2[q][k], w, c##q);
#define F8T1(q) c##q = fmaf(sT1[q][k], w, c##q);
#define F8G0(q) c##q = fmaf(sH0[q][jj], w, c##q);
#define L0S(q) sH0[q][j] = fast_tanh(c##q);
#define L1S(q) { float tv = fast_tanh(c##q); sT1[q][j] = tv; sH1[q][j] = sH0[q][j] + tv; }
#define L2S(q) { float tv = fast_tanh(c##q); sT2[q][j] = tv; atomicAdd(&sEi[q], (sH1[q][j] + tv) * w3); }
#define G2S(q) { float tv = sT2[q][j]; sT2[q][j] = w3 * (1.0f - tv * tv); }
#define D1S(q) { float dh1 = c##q; float tv = sT1[q][j]; sH1[q][j] = dh1; sT1[q][j] = dh1 * (1.0f - tv * tv); }
#define D0S(q) { float h0v = sH0[q][j]; sH0[q][j] = c##q * (1.0f - h0v * h0v); }
#define DXS(q) sX[q][i] = c##q;

// K2: 8 atoms per block. DRt + fitting net fwd + bwd -> Ei/Etot + dacc.
__global__ __launch_bounds__(256, 4) void k_fit(
    const float* __restrict__ acc_ws,
    const float* __restrict__ fW0, const float* __restrict__ fb0,
    const float* __restrict__ fW1, const float* __restrict__ fb1,
    const float* __restrict__ fW2, const float* __restrict__ fb2,
    const float* __restrict__ fW3, const float* __restrict__ fb3,
    const float* __restrict__ ener_shift,
    float* __restrict__ dacc_ws, float* __restrict__ out) {
  constexpr int AB = 8;
  __shared__ float sAcc[AB][100];
  __shared__ float sX[AB][400];
  __shared__ float sH0[AB][FH_];
  __shared__ float sT1[AB][FH_];
  __shared__ float sH1[AB][FH_];
  __shared__ float sT2[AB][FH_];
  __shared__ float sEi[AB];
  int a0 = blockIdx.x * AB;
  int bb = a0 >> 10;
  int n0 = a0 & (N_ - 1);
  int t = (n0 >= 512) ? 1 : 0;
  int tid = threadIdx.x;
  for (int idx = tid; idx < AB * 100; idx += 256)
    ((float*)sAcc)[idx] = acc_ws[a0 * 100 + idx];
  if (tid < AB) sEi[tid] = 0.0f;
  __syncthreads();
  for (int idx = tid; idx < AB * 400; idx += 256) {
    int a = idx / 400; int r = idx % 400; int e = r >> 4; int f = r & 15;
    const float* A = sAcc[a];
    sX[a][r] = A[e] * A[f] + A[25 + e] * A[25 + f] + A[50 + e] * A[50 + f] +
               A[75 + e] * A[75 + f];
  }
  __syncthreads();
  const float* W0 = fW0 + t * 400 * FH_;
  const float* W1 = fW1 + t * FH_ * FH_;
  const float* W2 = fW2 + t * FH_ * FH_;
  const float* B0 = fb0 + t * FH_;
  const float* B1 = fb1 + t * FH_;
  const float* B2 = fb2 + t * FH_;
  const float* W3 = fW3 + t * FH_;
  int j = tid;
  if (j < FH_) {  // layer 0: 400 -> 240
    DECL8(B0[j])
    for (int i = 0; i < 400; ++i) { float w = W0[i * FH_ + j]; AP8(F8X) }
    AP8(L0S)
  }
  __syncthreads();
  if (j < FH_) {  // layer 1 (residual)
    DECL8(B1[j])
    for (int f = 0; f < FH_; ++f) { float w = W1[f * FH_ + j]; AP8(F8H0) }
    AP8(L1S)
  }
  __syncthreads();
  if (j < FH_) {  // layer 2 (residual) + Ei dot
    DECL8(B2[j])
    for (int f = 0; f < FH_; ++f) { float w = W2[f * FH_ + j]; AP8(F8H1) }
    float w3 = W3[j];
    AP8(L2S)
  }
  __syncthreads();
  if (tid < AB) {
    float ei = sEi[tid] + fb3[t] + ener_shift[t];
    out[8 + a0 + tid] = ei;            // Ei
    sEi[tid] = ei;
  }
  if (j < FH_) {  // g2 = W3*(1 - t2^2)
    float w3 = W3[j];
    AP8(G2S)
  }
  __syncthreads();
  if (tid == 0) {
    float s = sEi[0] + sEi[1] + sEi[2] + sEi[3] + sEi[4] + sEi[5] + sEi[6] + sEi[7];
    atomicAdd(&out[bb], s);
  }
  if (j < FH_) {  // dh1 = W3 + g2 @ W2^T ; g1 = dh1*(1-t1^2)
    DECL8(W3[j])
    for (int k = 0; k < FH_; ++k) { float w = W2[j * FH_ + k]; AP8(F8T2) }
    AP8(D1S)
  }
  __syncthreads();
  if (j < FH_) {  // dh0 = dh1 + g1 @ W1^T ; g0 = dh0*(1-h0^2)
    DECL8(sH1[0][j])
    c1 = sH1[1][j]; c2 = sH1[2][j]; c3 = sH1[3][j];
    c4 = sH1[4][j]; c5 = sH1[5][j]; c6 = sH1[6][j]; c7 = sH1[7][j];
    for (int k = 0; k < FH_; ++k) { float w = W1[j * FH_ + k]; AP8(F8T1) }
    AP8(D0S)
  }
  __syncthreads();
  for (int i = tid; i < 400; i += 256) {  // dx = g0 @ W0^T
    DECL8(0.0f)
    for (int jj = 0; jj < FH_; ++jj) { float w = W0[i * FH_ + jj]; AP8(F8G0) }
    AP8(DXS)
  }
  __syncthreads();
  for (int idx = tid; idx < AB * 100; idx += 256) {
    int a = idx / 100; int r = idx % 100; int d = r / 25; int e = r % 25;
    const float* A = sAcc[a];
    const float* DX = sX[a];
    float sum = 0.0f;
#pragma unroll
    for (int f = 0; f < 16; ++f) sum = fmaf(DX[e * 16 + f], A[d * 25 + f], sum);
    if (e < 16) {
#pragma unroll
      for (int e2 = 0; e2 < 25; ++e2) sum = fmaf(DX[e2 * 16 + e], A[d * 25 + e2], sum);
    }
    dacc_ws[a0 * 100 + idx] = sum;
  }
}

// ---- K3 macro bodies: embed fwd + VJP, all named scalars ----
#define K3H0(e) float x##e = fast_tanh(fmaf(s0, W0p[e], b0p[e]));
#define K3A1(e) float a##e = b1p[e];
#define K3M1E(f,e) a##e = fmaf(hf, W1p[(f)*25+(e)], a##e);
#define K3M1R(f) { const float hf = x##f; RB(K3M1E, f) }
#define K3T1(e) float t##e = fast_tanh(a##e); x##e += t##e;
#define K3A2(e) a##e = b2p[e];
#define K3M2E(f,e) a##e = fmaf(hf, W2p[(f)*25+(e)], a##e);
#define K3M2R(f) { const float hf = x##f; RB(K3M2E, f) }
#define K3DY(e) float y##e;
#define K3SD(e) { float t2 = fast_tanh(a##e); float G = x##e + t2; \
  db0 = fmaf(dacp[e], G, db0); db1 = fmaf(dacp[25+(e)], G, db1); \
  db2 = fmaf(dacp[50+(e)], G, db2); db3 = fmaf(dacp[75+(e)], G, db3); \
  float dg = CSC * (dacp[e] * bb0 + dacp[25+(e)] * bb1 + \
                    dacp[50+(e)] * bb2 + dacp[75+(e)] * bb3); \
  y##e = dg * (1.0f - t2 * t2); a##e = dg; }
#define K3SEF(e,f) s = fmaf(y##f, W2p[(e)*25+(f)], s);
#define K3SE(e) { float s = a##e; RB(K3SEF, e) a##e = s; }
#define K3G1(e) y##e = a##e * (1.0f - t##e * t##e);
#define K3SFF(e,f) s = fmaf(y##f, W1p[(e)*25+(f)], s);
#define K3SF(e) { float s = a##e; RB(K3SFF, e) float h0e = x##e - t##e; \
  dsum = fmaf(s * (1.0f - h0e * h0e), W0p[e], dsum); }

// K3: per atom (block) x neighbor (thread): embed fwd + VJP -> dE -> forces.
__global__ __launch_bounds__(256, 2) void k_bwd_force(
    const float* __restrict__ dR, const int* __restrict__ neigh,
    const float* __restrict__ davg, const float* __restrict__ dstd,
    const float* __restrict__ eW0, const float* __restrict__ eb0,
    const float* __restrict__ eW1, const float* __restrict__ eb1,
    const float* __restrict__ eW2, const float* __restrict__ eb2,
    const float* __restrict__ dacc_ws, float* __restrict__ out) {
  __shared__ float sF[3];
  int atom = blockIdx.x;
  int bb = atom >> 10;
  int n = atom & (N_ - 1);
  int t = (n >= 512) ? 1 : 0;
  int m = threadIdx.x;
  if (m < 3) sF[m] = 0.0f;
  __syncthreads();
  int p = __builtin_amdgcn_readfirstlane(t * 2 + (m >> 7));  // wave-uniform
  const float* W0p = eW0 + p * D_;
  const float* b0p = eb0 + p * D_;
  const float* W1p = eW1 + p * 625;
  const float* b1p = eb1 + p * D_;
  const float* W2p = eW2 + p * 625;
  const float* b2p = eb2 + p * D_;
  const float* dacp = dacc_ws + atom * 100;  // block-uniform -> s_load
  int base = atom * M_ + m;
  float dx = dR[base * 3 + 0];
  float dy = dR[base * 3 + 1];
  float dz = dR[base * 3 + 2];
  int nb = neigh[base];
  float bb0, bb1, bb2, bb3;
  geom_blk(dx, dy, dz, nb, t, m, davg, dstd, bb0, bb1, bb2, bb3);
  float s0 = bb0;
  RA(K3H0)                 // x = h0
  RA(K3A1)                 // a = b1
  RA(K3M1R)                // a += h0 @ W1
  RA(K3T1)                 // t = tanh(a); x = h1
  RA(K3A2)                 // a = b2
  RA(K3M2R)                // a += h1 @ W2
  RA(K3DY)
  float db0 = 0.0f, db1 = 0.0f, db2 = 0.0f, db3 = 0.0f;
  RA(K3SD)                 // dblk accum; a := dG; y := g2
  RA(K3SE)                 // a := dh1 = dG + g2 @ W2^T
  RA(K3G1)                 // y := g1
  float dsum = 0.0f;
  RA(K3SF)                 // dsum = sum (dh0 gate) * W0
  float dE0 = db0 * CSC + dsum;
  float dE1 = db1 * CSC;
  float dE2 = db2 * CSC;
  float dE3 = db3 * CSC;
  float px, py, pz;
  geom_force(dx, dy, dz, nb, t, m, dstd, dE0, dE1, dE2, dE3, px, py, pz);
  // wave-level reduce for self-force, then one LDS atomic per wave
  float rx = px, ry = py, rz = pz;
#pragma unroll
  for (int off = 32; off > 0; off >>= 1) {
    rx += __shfl_down(rx, off, 64);
    ry += __shfl_down(ry, off, 64);
    rz += __shfl_down(rz, off, 64);
  }
  if ((m & 63) == 0) {
    atomicAdd(&sF[0], rx);
    atomicAdd(&sF[1], ry);
    atomicAdd(&sF[2], rz);
  }
  if (nb > 0) {  // scatter to neighbor j = nb-1
    int jn = nb - 1;
    int fi = 8 + NATOM + (bb * N_ + jn) * 3;
    atomicAdd(&out[fi + 0], px);
    atomicAdd(&out[fi + 1], py);
    atomicAdd(&out[fi + 2], pz);
  }
  __syncthreads();
  if (m < 3) atomicAdd(&out[8 + NATOM + atom * 3 + m], -sF[m]);
}

}  // namespace

extern "C" void kernel_launch(void* const* d_in, const int* in_sizes, int n_in,
                              void* d_out, int out_size, void* d_ws, size_t ws_size,
                              hipStream_t stream) {
  (void)in_sizes; (void)n_in; (void)ws_size;
  const float* image_dR   = (const float*)d_in[0];
  const int*   list_neigh = (const int*)d_in[1];
  const float* davg       = (const float*)d_in[2];
  const float* dstd       = (const float*)d_in[3];
  const float* eW0        = (const float*)d_in[4];
  const float* eb0        = (const float*)d_in[5];
  const float* eW1        = (const float*)d_in[6];
  const float* eb1        = (const float*)d_in[7];
  const float* eW2        = (const float*)d_in[8];
  const float* eb2        = (const float*)d_in[9];
  const float* fW0        = (const float*)d_in[10];
  const float* fb0        = (const float*)d_in[11];
  const float* fW1        = (const float*)d_in[12];
  const float* fb1        = (const float*)d_in[13];
  const float* fW2        = (const float*)d_in[14];
  const float* fb2        = (const float*)d_in[15];
  const float* fW3        = (const float*)d_in[16];
  const float* fb3        = (const float*)d_in[17];
  const float* ener_shift = (const float*)d_in[18];
  float* out = (float*)d_out;
  float* acc_ws  = (float*)d_ws;                  // 8192*100 floats
  float* dacc_ws = acc_ws + NATOM * 100;          // 8192*100 floats

  hipMemsetAsync(d_out, 0, (size_t)out_size * sizeof(float), stream);
  k_embed_acc<<<NATOM, 256, 0, stream>>>(image_dR, list_neigh, davg, dstd,
                                         eW0, eb0, eW1, eb1, eW2, eb2, acc_ws);
  k_fit<<<NATOM / 8, 256, 0, stream>>>(acc_ws, fW0, fb0, fW1, fb1, fW2, fb2,
                                       fW3, fb3, ener_shift, dacc_ws, out);
  k_bwd_force<<<NATOM, 256, 0, stream>>>(image_dR, list_neigh, davg, dstd,
                                         eW0, eb0, eW1, eb1, eW2, eb2,
                                         dacc_ws, out);
}